// Round 1
// 528.562 us; speedup vs baseline: 1.0215x; 1.0215x over previous
//
#include <hip/hip_runtime.h>
#include <hip/hip_bf16.h>
#include <stdint.h>

// MoE FFN top-2 sparse, bf16 MFMA, global_load_lds staging. T=4096, D=1024, H=2816, E=8.
// Round 5: BK=64 K-steps (half the barrier drains) + XOR chunk swizzle
// (pre-swizzled global source, swizzled ds_read) for both ffn kernels.
//
// ws layout (needs 193,167,872 B):
//   [0]         counts[8]
//   [256]       offs[8]
//   [512]       tlist[E*T] int        131072
//   [131584]    re[2T] int            32768   (expert per token slot)
//   [164352]    rs[2T] int            32768   (slot within expert list)
//   [197120]    rw[2T] float          32768   (gate weight)
//   [229888]    xbf[T*D] bf16         8388608
//   [8618496]   hmat[8192*H] bf16     46137344
//   [54755840]  W3bf bf16             46137344
//   [100893184] W1bf bf16             46137344   <-- ypart0[8192*D] fp32 aliases after ffn1
//   [147030528] W2bf bf16             46137344   <-- ypart1[8192*D] fp32 aliases after ffn1

#define T_TOK 4096
#define DDIM 1024
#define HDIM 2816
#define NEXP 8

typedef __attribute__((ext_vector_type(8))) short short8;
typedef __attribute__((ext_vector_type(4))) short short4v;
typedef __attribute__((ext_vector_type(4))) float floatx4;

__device__ __forceinline__ short f2bf(float f) {
  union { float f; unsigned int u; } v; v.f = f;
  unsigned int u = v.u;
  u += 0x7FFFu + ((u >> 16) & 1u);   // round-to-nearest-even
  return (short)(u >> 16);
}

// async global->LDS, 16B per lane. LDS dest = wave-uniform base + lane*16.
__device__ __forceinline__ void gl2lds16(const void* g, void* l) {
  __builtin_amdgcn_global_load_lds(
      (const __attribute__((address_space(1))) void*)g,
      (__attribute__((address_space(3))) void*)l, 16, 0, 0);
}

// fp32 -> bf16 weight conversion. Coalesced: 16B/lane float4 read, 8B/lane write,
// grid-stride. blockIdx.y picks W1/W2/W3.
#define CONV_ELEM4 5767168   // (8*2816*1024)/4 float4s per matrix
__global__ __launch_bounds__(256) void convert_kernel(
    const float* __restrict__ W1, const float* __restrict__ W2, const float* __restrict__ W3,
    short* __restrict__ W1bf, short* __restrict__ W2bf, short* __restrict__ W3bf) {
  int z = blockIdx.y;
  const float4* src = (const float4*)((z == 0) ? W1 : (z == 1) ? W2 : W3);
  short4v* dst = (short4v*)((z == 0) ? W1bf : (z == 1) ? W2bf : W3bf);
  size_t stride = (size_t)gridDim.x * 256;
  for (size_t i = (size_t)blockIdx.x * 256 + threadIdx.x; i < CONV_ELEM4; i += stride) {
    float4 v = src[i];
    dst[i] = (short4v){f2bf(v.x), f2bf(v.y), f2bf(v.z), f2bf(v.w)};
  }
}

// gating scores + top-2 selection. 4 tokens per 256-thread block, one wave each.
// NO atomics: emits per-token (expert, weight) pairs re/rw + bf16 cast of x.
__global__ __launch_bounds__(256) void gating_score_kernel(const float* __restrict__ x,
    const float* __restrict__ Wg, short* __restrict__ xbf,
    int* __restrict__ re, float* __restrict__ rw) {
  int t = blockIdx.x * 4 + (threadIdx.x >> 6);
  int lane = threadIdx.x & 63;
  const float* xt = x + (size_t)t * DDIM;
  float xr[16];
#pragma unroll
  for (int j = 0; j < 16; ++j) xr[j] = xt[j * 64 + lane];
  short* xbt = xbf + (size_t)t * DDIM;
#pragma unroll
  for (int j = 0; j < 16; ++j) xbt[j * 64 + lane] = f2bf(xr[j]);
  float s[NEXP];
#pragma unroll
  for (int e = 0; e < NEXP; ++e) {
    const float* wge = Wg + e * DDIM;
    float p = 0.f;
#pragma unroll
    for (int j = 0; j < 16; ++j) p += xr[j] * wge[j * 64 + lane];
#pragma unroll
    for (int o = 32; o > 0; o >>= 1) p += __shfl_xor(p, o, 64);
    s[e] = p;
  }
  if (lane == 0) {
    int e1 = 0; float s1 = s[0];
#pragma unroll
    for (int e = 1; e < NEXP; ++e) if (s[e] > s1) { s1 = s[e]; e1 = e; }
    int e2 = -1; float s2 = -1e30f;
#pragma unroll
    for (int e = 0; e < NEXP; ++e) if (e != e1 && s[e] > s2) { s2 = s[e]; e2 = e; }
    re[2 * t] = e1;     rw[2 * t] = s1;
    re[2 * t + 1] = e2; rw[2 * t + 1] = s2;
  }
}

// Deterministic routing build, single workgroup, zero global atomics.
__global__ __launch_bounds__(1024) void route_kernel(const int* __restrict__ re,
    int* __restrict__ counts, int* __restrict__ offs,
    int* __restrict__ rs, int* __restrict__ tlist) {
  __shared__ int H[NEXP * 1024];   // 32 KiB
  __shared__ int totS[NEXP];
  int tid = threadIdx.x;
  int myre[8];
  int cnt[NEXP];
#pragma unroll
  for (int e = 0; e < NEXP; ++e) cnt[e] = 0;
  const int4* re4 = (const int4*)(re + tid * 8);
  int4 a = re4[0], b = re4[1];
  myre[0] = a.x; myre[1] = a.y; myre[2] = a.z; myre[3] = a.w;
  myre[4] = b.x; myre[5] = b.y; myre[6] = b.z; myre[7] = b.w;
#pragma unroll
  for (int j = 0; j < 8; ++j) cnt[myre[j]]++;
#pragma unroll
  for (int e = 0; e < NEXP; ++e) H[e * 1024 + tid] = cnt[e];
  __syncthreads();
  int wave = tid >> 6, lane = tid & 63;
  if (wave < NEXP) {
    int run = 0;
    for (int c = 0; c < 16; ++c) {
      int i = c * 64 + lane;
      int v = H[wave * 1024 + i];
      int sc = v;
#pragma unroll
      for (int o = 1; o < 64; o <<= 1) {
        int u = __shfl_up(sc, o, 64);
        if (lane >= o) sc += u;
      }
      int tot = __shfl(sc, 63, 64);
      H[wave * 1024 + i] = run + sc - v;   // exclusive prefix within expert
      run += tot;
    }
    if (lane == 0) totS[wave] = run;
  }
  __syncthreads();
  if (tid == 0) {
    int run = 0;
    for (int e = 0; e < NEXP; ++e) {
      offs[e] = run; counts[e] = totS[e]; run += totS[e];
    }
  }
  int pos[NEXP];
#pragma unroll
  for (int e = 0; e < NEXP; ++e) pos[e] = H[e * 1024 + tid];
#pragma unroll
  for (int j = 0; j < 8; ++j) {
    int e = myre[j];
    int slot = pos[e]++;
    int idx = tid * 8 + j;
    rs[idx] = slot;
    tlist[e * T_TOK + slot] = idx >> 1;
  }
}

// ffn1: hmat[row, h] = silu(x@W1^T) * (x@W2^T). BM=128 x BN=64 x BK=64, 4 waves 2x2,
// dual accumulators. LDS rows are 64 shorts (128B = full bank span), so chunks are
// XOR-swizzled: LDS chunk p of row r holds global 16B-chunk p^(r&7). global_load_lds
// writes linearly; the swizzle is applied on the per-lane GLOBAL source address and
// undone on the ds_read address (same involution both sides).
__global__ __launch_bounds__(256) void ffn1_fast_kernel(const short* __restrict__ xbf,
    const short* __restrict__ W1bf, const short* __restrict__ W2bf,
    const int* __restrict__ counts, const int* __restrict__ offs,
    const int* __restrict__ tlist, short* __restrict__ hmat) {
  int e = blockIdx.z;
  int cnt = counts[e];
  int m0 = blockIdx.y * 128;
  if (m0 >= cnt) return;
  int n0 = blockIdx.x * 64;
  __shared__ __attribute__((aligned(16))) short As[128 * 64];   // 16 KiB
  __shared__ __attribute__((aligned(16))) short Bs1[64 * 64];   //  8 KiB
  __shared__ __attribute__((aligned(16))) short Bs2[64 * 64];   //  8 KiB
  __shared__ int toks[128];
  int tid = threadIdx.x;
  if (tid < 128) {
    int m = m0 + tid;
    toks[tid] = tlist[e * T_TOK + (m < cnt ? m : cnt - 1)];
  }
  __syncthreads();
  int lane = tid & 63, w = tid >> 6;
  int wr = w >> 1, wc = w & 1;
  int lrow = lane & 15, lq = lane >> 4;
  int sr = lane >> 3;            // 0..7: row within an 8-row staging call
  int sc = lane & 7;             // 0..7: 16B chunk within a 128B row
  int scs = ((sc ^ sr) & 7) * 8; // swizzled source chunk (short offset)
  // A staging: wave w owns rows [w*32, w*32+32), 4 calls x 8 rows. row&7 == sr.
  const short* pA[4];
#pragma unroll
  for (int j = 0; j < 4; ++j)
    pA[j] = xbf + (size_t)toks[w * 32 + j * 8 + sr] * DDIM + scs;
  const short* b1e = W1bf + (size_t)e * HDIM * DDIM;
  const short* b2e = W2bf + (size_t)e * HDIM * DDIM;
  const short* pB1[2]; const short* pB2[2];
#pragma unroll
  for (int j = 0; j < 2; ++j) {
    int row = w * 16 + j * 8 + sr;
    pB1[j] = b1e + (size_t)(n0 + row) * DDIM + scs;
    pB2[j] = b2e + (size_t)(n0 + row) * DDIM + scs;
  }
  void* lA[4]; void* lB1[2]; void* lB2[2];
#pragma unroll
  for (int j = 0; j < 4; ++j) lA[j] = (void*)&As[(w * 32 + j * 8) * 64];
#pragma unroll
  for (int j = 0; j < 2; ++j) {
    lB1[j] = (void*)&Bs1[(w * 16 + j * 8) * 64];
    lB2[j] = (void*)&Bs2[(w * 16 + j * 8) * 64];
  }
  floatx4 accg[4][2], accu[4][2];
#pragma unroll
  for (int i = 0; i < 4; ++i)
#pragma unroll
    for (int j = 0; j < 2; ++j) {
      accg[i][j] = (floatx4){0.f, 0.f, 0.f, 0.f};
      accu[i][j] = (floatx4){0.f, 0.f, 0.f, 0.f};
    }
  for (int kk = 0; kk < DDIM; kk += 64) {
#pragma unroll
    for (int j = 0; j < 4; ++j) { gl2lds16(pA[j], lA[j]); pA[j] += 64; }
#pragma unroll
    for (int j = 0; j < 2; ++j) {
      gl2lds16(pB1[j], lB1[j]); pB1[j] += 64;
      gl2lds16(pB2[j], lB2[j]); pB2[j] += 64;
    }
    __syncthreads();
#pragma unroll
    for (int kh = 0; kh < 2; ++kh) {
      int csw = (((kh * 4 + lq) ^ (lrow & 7)) & 7) * 8;  // un-swizzle on read
      short8 a[4], b1[2], b2[2];
#pragma unroll
      for (int mf = 0; mf < 4; ++mf)
        a[mf] = *(short8*)&As[(wr * 64 + mf * 16 + lrow) * 64 + csw];
#pragma unroll
      for (int nf = 0; nf < 2; ++nf) {
        b1[nf] = *(short8*)&Bs1[(wc * 32 + nf * 16 + lrow) * 64 + csw];
        b2[nf] = *(short8*)&Bs2[(wc * 32 + nf * 16 + lrow) * 64 + csw];
      }
#pragma unroll
      for (int mf = 0; mf < 4; ++mf)
#pragma unroll
        for (int nf = 0; nf < 2; ++nf) {
          accg[mf][nf] = __builtin_amdgcn_mfma_f32_16x16x32_bf16(a[mf], b1[nf], accg[mf][nf], 0, 0, 0);
          accu[mf][nf] = __builtin_amdgcn_mfma_f32_16x16x32_bf16(a[mf], b2[nf], accu[mf][nf], 0, 0, 0);
        }
    }
    __syncthreads();
  }
  int base = offs[e];
#pragma unroll
  for (int mf = 0; mf < 4; ++mf)
#pragma unroll
    for (int r = 0; r < 4; ++r) {
      int mloc = wr * 64 + mf * 16 + lq * 4 + r;
      if (m0 + mloc < cnt) {
        size_t row = (size_t)(base + m0 + mloc);
#pragma unroll
        for (int nf = 0; nf < 2; ++nf) {
          float g = accg[mf][nf][r];
          float u = accu[mf][nf][r];
          float h = g / (1.f + __expf(-g)) * u;
          hmat[row * HDIM + n0 + wc * 32 + nf * 16 + lrow] = f2bf(h);
        }
      }
    }
}

// ffn2: split-K x2. ypart[ks][row, :] = hmat_row[khalf] @ W3[khalf]^T.
// BM=128 x BN=128 x BK=64, same XOR-swizzled staging as ffn1.
#define KSPLIT 2
#define KHALF (HDIM / KSPLIT)   // 1408 = 22*64
__global__ __launch_bounds__(256) void ffn2_fast_kernel(const short* __restrict__ hmat,
    const short* __restrict__ W3bf,
    const int* __restrict__ counts, const int* __restrict__ offs,
    float* __restrict__ ypart0, float* __restrict__ ypart1) {
  int e = blockIdx.z;
  int cnt = counts[e];
  int m0 = blockIdx.y * 128;
  if (m0 >= cnt) return;
  int ks = blockIdx.x >> 3;            // 0..1: K-split index
  int n0 = (blockIdx.x & 7) * 128;     // 0..7: n-tile
  int k0 = ks * KHALF;
  float* ypart = ks ? ypart1 : ypart0;
  int base = offs[e];
  __shared__ __attribute__((aligned(16))) short As[128 * 64];   // 16 KiB
  __shared__ __attribute__((aligned(16))) short Bs[128 * 64];   // 16 KiB
  int tid = threadIdx.x;
  int lane = tid & 63, w = tid >> 6;
  int wr = w >> 1, wc = w & 1;
  int lrow = lane & 15, lq = lane >> 4;
  int sr = lane >> 3;
  int sc = lane & 7;
  int scs = ((sc ^ sr) & 7) * 8;
  const short* W3e = W3bf + (size_t)e * DDIM * HDIM;
  const short* pA[4]; const short* pB[4];
  void* lA[4]; void* lB[4];
#pragma unroll
  for (int j = 0; j < 4; ++j) {
    int gr = m0 + w * 32 + j * 8 + sr;
    gr = gr < cnt ? gr : cnt - 1;
    pA[j] = hmat + (size_t)(base + gr) * HDIM + k0 + scs;
    pB[j] = W3e + (size_t)(n0 + w * 32 + j * 8 + sr) * HDIM + k0 + scs;
    lA[j] = (void*)&As[(w * 32 + j * 8) * 64];
    lB[j] = (void*)&Bs[(w * 32 + j * 8) * 64];
  }
  floatx4 acc[4][4];
#pragma unroll
  for (int i = 0; i < 4; ++i)
#pragma unroll
    for (int j = 0; j < 4; ++j) acc[i][j] = (floatx4){0.f, 0.f, 0.f, 0.f};
  for (int kk = 0; kk < KHALF; kk += 64) {
#pragma unroll
    for (int j = 0; j < 4; ++j) { gl2lds16(pA[j], lA[j]); pA[j] += 64; }
#pragma unroll
    for (int j = 0; j < 4; ++j) { gl2lds16(pB[j], lB[j]); pB[j] += 64; }
    __syncthreads();
#pragma unroll
    for (int kh = 0; kh < 2; ++kh) {
      int csw = (((kh * 4 + lq) ^ (lrow & 7)) & 7) * 8;
      short8 a[4], b[4];
#pragma unroll
      for (int mf = 0; mf < 4; ++mf)
        a[mf] = *(short8*)&As[(wr * 64 + mf * 16 + lrow) * 64 + csw];
#pragma unroll
      for (int nf = 0; nf < 4; ++nf)
        b[nf] = *(short8*)&Bs[(wc * 64 + nf * 16 + lrow) * 64 + csw];
#pragma unroll
      for (int mf = 0; mf < 4; ++mf)
#pragma unroll
        for (int nf = 0; nf < 4; ++nf)
          acc[mf][nf] = __builtin_amdgcn_mfma_f32_16x16x32_bf16(a[mf], b[nf], acc[mf][nf], 0, 0, 0);
    }
    __syncthreads();
  }
#pragma unroll
  for (int mf = 0; mf < 4; ++mf)
#pragma unroll
    for (int r = 0; r < 4; ++r) {
      int mloc = wr * 64 + mf * 16 + lq * 4 + r;
      if (m0 + mloc < cnt) {
        float* orow = ypart + (size_t)(base + m0 + mloc) * DDIM + n0 + wc * 64 + lrow;
#pragma unroll
        for (int nf = 0; nf < 4; ++nf)
          orow[nf * 16] = acc[mf][nf][r];
      }
    }
}

// out[t,:] = w0*(y0[r0]+y1[r0]) + w1*(y0[r1]+y1[r1])  (overwrites out; no atomics)
__global__ __launch_bounds__(256) void combine_kernel(const float4* __restrict__ y0,
    const float4* __restrict__ y1,
    const int* __restrict__ offs, const int* __restrict__ re, const int* __restrict__ rs,
    const float* __restrict__ rw, float4* __restrict__ out4) {
  int t = blockIdx.x;
  int i = threadIdx.x;
  size_t r0 = (size_t)(offs[re[2 * t]] + rs[2 * t]) * 256 + i;
  size_t r1 = (size_t)(offs[re[2 * t + 1]] + rs[2 * t + 1]) * 256 + i;
  float w0 = rw[2 * t], w1 = rw[2 * t + 1];
  float4 a0 = y0[r0], a1 = y1[r0];
  float4 b0 = y0[r1], b1 = y1[r1];
  out4[(size_t)t * 256 + i] = make_float4(
      w0 * (a0.x + a1.x) + w1 * (b0.x + b1.x),
      w0 * (a0.y + a1.y) + w1 * (b0.y + b1.y),
      w0 * (a0.z + a1.z) + w1 * (b0.z + b1.z),
      w0 * (a0.w + a1.w) + w1 * (b0.w + b1.w));
}

extern "C" void kernel_launch(void* const* d_in, const int* in_sizes, int n_in,
                              void* d_out, int out_size, void* d_ws, size_t ws_size,
                              hipStream_t stream) {
  const float* x  = (const float*)d_in[0];
  const float* Wg = (const float*)d_in[1];
  const float* W1 = (const float*)d_in[2];
  const float* W2 = (const float*)d_in[3];
  const float* W3 = (const float*)d_in[4];
  float* out = (float*)d_out;
  char* ws = (char*)d_ws;

  int*   counts = (int*)(ws + 0);
  int*   offs   = (int*)(ws + 256);
  int*   tlist  = (int*)(ws + 512);
  int*   re     = (int*)(ws + 131584);
  int*   rs     = (int*)(ws + 164352);
  float* rw     = (float*)(ws + 197120);
  short* xbf    = (short*)(ws + 229888);
  short* hmat   = (short*)(ws + 8618496);
  short* W3bf   = (short*)(ws + 54755840);
  short* W1bf   = (short*)(ws + 100893184);
  short* W2bf   = (short*)(ws + 147030528);
  float* ypart0 = (float*)(ws + 100893184);   // aliases W1bf (dead after ffn1)
  float* ypart1 = (float*)(ws + 147030528);   // aliases W2bf (dead after ffn1)

  convert_kernel<<<dim3(4096, 3), 256, 0, stream>>>(W1, W2, W3, W1bf, W2bf, W3bf);
  gating_score_kernel<<<T_TOK / 4, 256, 0, stream>>>(x, Wg, xbf, re, rw);
  route_kernel<<<1, 1024, 0, stream>>>(re, counts, offs, rs, tlist);
  ffn1_fast_kernel<<<dim3(HDIM / 64, T_TOK / 128, NEXP), 256, 0, stream>>>(
      xbf, W1bf, W2bf, counts, offs, tlist, hmat);
  ffn2_fast_kernel<<<dim3((DDIM / 128) * KSPLIT, T_TOK / 128, NEXP), 256, 0, stream>>>(
      hmat, W3bf, counts, offs, ypart0, ypart1);
  combine_kernel<<<T_TOK, 256, 0, stream>>>((const float4*)ypart0, (const float4*)ypart1,
                                            offs, re, rs, rw, (float4*)out);
}